// Round 5
// baseline (67.570 us; speedup 1.0000x reference)
//
#include <hip/hip_runtime.h>
#include <hip/hip_bf16.h>

// Locally-connected 2D: out[b,o,y,x] = sum_{c,kh,kw} x[b,c,y+kh,x+kw] * W[y,x,o,c*25+kh*5+kw] + b[y,x,o]
// x: [128,3,64,64] f32, W: [60,60,32,75] f32, bias: [60,60,32] f32, out: [128,32,60,60] f32.
//
// Phase 1 (k1): one block per position (3600 blocks). GEMM M=128,N=32,K=75 (pad 96),
// bf16 MFMA 16x16x32. Natural k-order (no shift copies / LUT): W stages linearly.
// LDS 30.7KB -> 5 blocks/CU; ONE barrier per block (stagers write the pad zeros).
// Epilogue writes tmp[pos][b*32+o] fully coalesced; k2 transposes tmp -> out.

#define RY 60
#define RX 60
#define OC 32
#define BATCH 128
#define CIN 3
#define HW 64
#define KLD 96    // padded K (bf16 row stride 192 B)

typedef __attribute__((ext_vector_type(8))) short short8;
typedef __attribute__((ext_vector_type(4))) float f32x4;

__device__ __forceinline__ ushort bf16u(float f) {
    __hip_bfloat16 h = __float2bfloat16(f);       // HW v_cvt (RNE)
    return *reinterpret_cast<ushort*>(&h);
}

template<bool COAL>
__global__ __launch_bounds__(256, 5) void lc2d_k1(
    const float* __restrict__ x, const float* __restrict__ w,
    const float* __restrict__ bias, float* __restrict__ outp,
    float* __restrict__ tmp)
{
    __shared__ ushort pa[BATCH][KLD];   // 24576 B
    __shared__ ushort wt[OC][KLD];      //  6144 B   (total 30720 -> 5 blocks/CU)

    const int tid = threadIdx.x;
    // XCD-chunked mapping: 3600 = 8 x 450; x-major within chunk so x/y-adjacent
    // positions share an XCD L2 (x reuse + tmp-line locality). Bijective.
    const int id  = blockIdx.x;
    const int lin = (id & 7) * 450 + (id >> 3);
    const int xx  = lin % RX;
    const int y   = lin / RX;
    const int pos = y * RX + xx;

    // ---------------- stage W (linear copy, float4 loads, HW bf16 cvt) ----------------
    const float4* w4 = (const float4*)(w + (size_t)pos * (OC * 75));  // 9600B, 16B-aligned
    #pragma unroll
    for (int m = 0; m < 3; ++m) {
        const int idx = tid + m * 256;
        if (idx < 600) {
            const float4 v = w4[idx];
            const int k0 = idx * 4;
            #pragma unroll
            for (int j = 0; j < 4; ++j) {
                const int k  = k0 + j;
                const int o  = k / 75;            // magic-mul
                const int km = k - o * 75;
                const float f = (j == 0) ? v.x : (j == 1) ? v.y : (j == 2) ? v.z : v.w;
                wt[o][km] = bf16u(f);
            }
        }
    }
    // wt pad zeros [75,96)
    if (tid < OC) {
        wt[tid][75] = 0;
        unsigned* z = (unsigned*)&wt[tid][76];
        #pragma unroll
        for (int j = 0; j < 10; ++j) z[j] = 0u;
    }

    // ---------------- stage patches: 1920 rows (b,c,kh) x 5 floats ----------------
    // aligned float2 loads from even base, shift-select by (xx&1)
    const int e  = xx & ~1;
    const int sh = xx & 1;
    for (int r = tid; r < BATCH * CIN * 5; r += 256) {
        const int b  = r / 15;
        const int cm = r % 15;
        const int c  = cm / 5;
        const int kh = cm % 5;
        const float* src = x + (size_t)((b * CIN + c) * HW + (y + kh)) * HW + e;
        const float2 v0 = *(const float2*)(src);
        const float2 v1 = *(const float2*)(src + 2);
        const float2 v2 = *(const float2*)(src + 4);
        float f[6] = {v0.x, v0.y, v1.x, v1.y, v2.x, v2.y};
        ushort* dst = &pa[b][c * 25 + kh * 5];
        #pragma unroll
        for (int i = 0; i < 5; ++i) dst[i] = bf16u(f[i + sh]);
        if (cm == 14) {            // this row's thread also zeroes pa[b][75..96)
            pa[b][75] = 0;
            unsigned* z = (unsigned*)&pa[b][76];
            #pragma unroll
            for (int j = 0; j < 10; ++j) z[j] = 0u;
        }
    }
    __syncthreads();

    // ---------------- MFMA: wave wid owns rows [wid*32,+32) x 2 N-tiles ----------------
    const int wid  = tid >> 6;
    const int lane = tid & 63;
    const int lrow = lane & 15;
    const int lgrp = lane >> 4;
    const int mbase = wid * 32;

    // bias for this lane's two o-columns (issue early; used in epilogue)
    const float bv0 = bias[(size_t)pos * OC + lrow];
    const float bv1 = bias[(size_t)pos * OC + 16 + lrow];

    f32x4 acc[2][2];
    #pragma unroll
    for (int mt = 0; mt < 2; ++mt)
        #pragma unroll
        for (int nt = 0; nt < 2; ++nt)
            acc[mt][nt] = (f32x4){0.f, 0.f, 0.f, 0.f};

    #pragma unroll
    for (int ks = 0; ks < 3; ++ks) {
        const int koff = ks * 32 + lgrp * 8;
        const short8 af0 = *(const short8*)&pa[mbase + lrow][koff];
        const short8 af1 = *(const short8*)&pa[mbase + 16 + lrow][koff];
        const short8 bf0 = *(const short8*)&wt[lrow][koff];
        const short8 bf1 = *(const short8*)&wt[16 + lrow][koff];
        acc[0][0] = __builtin_amdgcn_mfma_f32_16x16x32_bf16(af0, bf0, acc[0][0], 0, 0, 0);
        acc[0][1] = __builtin_amdgcn_mfma_f32_16x16x32_bf16(af0, bf1, acc[0][1], 0, 0, 0);
        acc[1][0] = __builtin_amdgcn_mfma_f32_16x16x32_bf16(af1, bf0, acc[1][0], 0, 0, 0);
        acc[1][1] = __builtin_amdgcn_mfma_f32_16x16x32_bf16(af1, bf1, acc[1][1], 0, 0, 0);
    }

    if (COAL) {
        // tmp[pos][b*32+o]: block writes 16KB contiguous; wave stores 4x64B segments
        float* tb = tmp + (size_t)pos * (BATCH * OC);
        #pragma unroll
        for (int mt = 0; mt < 2; ++mt) {
            #pragma unroll
            for (int nt = 0; nt < 2; ++nt) {
                const float bv = nt ? bv1 : bv0;
                const int o = nt * 16 + lrow;
                #pragma unroll
                for (int r = 0; r < 4; ++r) {
                    const int b = mbase + mt * 16 + lgrp * 4 + r;
                    tb[b * OC + o] = acc[mt][nt][r] + bv;
                }
            }
        }
    } else {
        #pragma unroll
        for (int mt = 0; mt < 2; ++mt) {
            #pragma unroll
            for (int nt = 0; nt < 2; ++nt) {
                const float bv = nt ? bv1 : bv0;
                const int o = nt * 16 + lrow;
                #pragma unroll
                for (int r = 0; r < 4; ++r) {
                    const int b = mbase + mt * 16 + lgrp * 4 + r;
                    outp[(size_t)(b * OC + o) * (RY * RX) + pos] = acc[mt][nt][r] + bv;
                }
            }
        }
    }
}

// Phase 2: tmp[y*60+x][c] -> out[c][y*60+x], c = b*32+o in [0,4096)
__global__ __launch_bounds__(256) void lc2d_k2(
    const float* __restrict__ tmp, float* __restrict__ out)
{
    __shared__ float tile[64][61];
    const int y  = blockIdx.y;
    const int cb = blockIdx.x * 64;

    for (int i = threadIdx.x; i < RX * 16; i += 256) {
        const int xx  = i >> 4;
        const int cl4 = (i & 15) * 4;
        const float4 v = *(const float4*)(tmp + (size_t)(y * RX + xx) * (BATCH * OC) + cb + cl4);
        tile[cl4][xx]     = v.x;
        tile[cl4 + 1][xx] = v.y;
        tile[cl4 + 2][xx] = v.z;
        tile[cl4 + 3][xx] = v.w;
    }
    __syncthreads();

    for (int i = threadIdx.x; i < 64 * RX; i += 256) {
        const int cl = i / RX;
        const int xx = i % RX;
        out[(size_t)(cb + cl) * (RY * RX) + y * RX + xx] = tile[cl][xx];
    }
}

extern "C" void kernel_launch(void* const* d_in, const int* in_sizes, int n_in,
                              void* d_out, int out_size, void* d_ws, size_t ws_size,
                              hipStream_t stream) {
    const float* x    = (const float*)d_in[0];
    const float* w    = (const float*)d_in[1];
    const float* bias = (const float*)d_in[2];
    float* out        = (float*)d_out;
    float* tmp        = (float*)d_ws;

    const size_t tmp_bytes = (size_t)RY * RX * BATCH * OC * sizeof(float); // 59 MB

    if (ws_size >= tmp_bytes) {
        lc2d_k1<true><<<3600, 256, 0, stream>>>(x, w, bias, out, tmp);
        lc2d_k2<<<dim3(64, RY), 256, 0, stream>>>(tmp, out);
    } else {
        lc2d_k1<false><<<3600, 256, 0, stream>>>(x, w, bias, out, tmp);
    }
}

// Round 6
// 50.090 us; speedup vs baseline: 1.3490x; 1.3490x over previous
//
#include <hip/hip_runtime.h>
#include <hip/hip_bf16.h>

// Locally-connected 2D: out[b,o,y,x] = sum_{c,kh,kw} x[b,c,y+kh,x+kw] * W[y,x,o,c*25+kh*5+kw] + b[y,x,o]
// x: [128,3,64,64] f32, W: [60,60,32,75] f32, bias: [60,60,32] f32, out: [128,32,60,60] f32.
//
// k1: one block = 4 consecutive x positions (900 blocks). k-order k'=(c*5+kh)*8+w,
// w in [0,8) = x-window offset -> ONE patch staging (1920 x ds_write_b128) serves all
// 4 positions; A-fragments hoisted to registers once. W staged per position as
// (o, c*5+kh)-groups: 5 scalar loads -> shift-masked 8-slot b128 write (zeros inline).
// wt double-buffered: stage xi+1 overlaps MFMA of xi; one barrier per position.
// K'=120 (pad 128) -> 4 MFMA K-steps. Epilogue -> tmp[pos][b*32+o] (coalesced);
// k2 transposes tmp -> out. Fallback: direct scatter if ws too small.

#define RY 60
#define RX 60
#define OC 32
#define BATCH 128
#define CIN 3
#define HW 64
#define XT 4
#define KP 136   // row stride (u16): 272 B -> 2-way-max bank aliasing; [120,136) zero pad

typedef __attribute__((ext_vector_type(8))) short short8;
typedef __attribute__((ext_vector_type(4))) float f32x4;

__device__ __forceinline__ ushort bf16u(float f) {
    __hip_bfloat16 h = __float2bfloat16(f);
    return *reinterpret_cast<ushort*>(&h);
}
__device__ __forceinline__ unsigned pk2(float a, float b) {
    return (unsigned)bf16u(a) | ((unsigned)bf16u(b) << 16);
}

// Stage one position's W into wtb: group g=(o, cm=c*5+kh); slots w=xj+kw get W[kw], rest 0.
__device__ __forceinline__ void stage_w(const float* __restrict__ wpos, int tid,
                                        ushort (*__restrict__ wtb)[KP], int xj)
{
    #pragma unroll
    for (int p = 0; p < 2; ++p) {
        const int g = tid + p * 256;
        if (g < 480) {
            const int o  = g / 15;
            const int cm = g - o * 15;
            const float* s = wpos + o * 75 + cm * 5;
            const ushort h[5] = {bf16u(s[0]), bf16u(s[1]), bf16u(s[2]),
                                 bf16u(s[3]), bf16u(s[4])};
            unsigned wd[4] = {0u, 0u, 0u, 0u};
            #pragma unroll
            for (int kw = 0; kw < 5; ++kw) {
                const int ww = xj + kw;              // xj is compile-time in unrolled caller
                wd[ww >> 1] |= (unsigned)h[kw] << ((ww & 1) * 16);
            }
            *reinterpret_cast<uint4*>(&wtb[o][cm * 8]) =
                make_uint4(wd[0], wd[1], wd[2], wd[3]);
        }
    }
}

template<bool COAL>
__global__ __launch_bounds__(256, 3) void lc2d_k1(
    const float* __restrict__ x, const float* __restrict__ w,
    const float* __restrict__ bias, float* __restrict__ outp,
    float* __restrict__ tmp)
{
    __shared__ ushort pa[BATCH][KP];   // 34816 B
    __shared__ ushort wt[2][OC][KP];   // 17408 B  (total 52224 -> 3 blocks/CU)

    const int tid = threadIdx.x;
    // bijective XCD swizzle for 900 blocks: q=112, r=4 (m204 variant)
    const int id  = blockIdx.x;
    const int xcd = id & 7, ii = id >> 3;
    const int lin = (xcd < 4 ? xcd * 113 : 452 + (xcd - 4) * 112) + ii;
    const int y   = lin / 15;
    const int xg  = lin - y * 15;
    const int x0  = xg * 4;
    const int pos0 = y * RX + x0;

    const int lane = tid & 63;
    const int lrow = lane & 15;
    const int lgrp = lane >> 4;
    const int wid  = tid >> 6;
    const int mbase = wid * 32;

    // ---- bias prefetch (issue early) ----
    float bb[XT][2];
    #pragma unroll
    for (int xi = 0; xi < XT; ++xi) {
        bb[xi][0] = bias[(size_t)(pos0 + xi) * OC + lrow];
        bb[xi][1] = bias[(size_t)(pos0 + xi) * OC + 16 + lrow];
    }

    // ---- stage patches once for all 4 positions: row = (b, cm=c*5+kh), 8 floats ----
    #pragma unroll
    for (int i = 0; i < 8; ++i) {
        const int r = tid + i * 256;
        if (i < 7 || r < BATCH * 15) {
            const int b  = r / 15;
            const int cm = r - b * 15;
            const int c  = cm / 5;
            const int kh = cm - c * 5;
            const float* src = x + (size_t)((b * CIN + c) * HW + (y + kh)) * HW + x0;
            const float4 v0 = *(const float4*)(src);       // x0 % 4 == 0 -> 16B aligned
            const float4 v1 = *(const float4*)(src + 4);
            *reinterpret_cast<uint4*>(&pa[b][cm * 8]) =
                make_uint4(pk2(v0.x, v0.y), pk2(v0.z, v0.w),
                           pk2(v1.x, v1.y), pk2(v1.z, v1.w));
        }
    }
    // ---- zero pads: pa[b][120..136), wt[buf][o][120..136) ----
    if (tid < 128) {
        *reinterpret_cast<uint4*>(&pa[tid][120]) = make_uint4(0u, 0u, 0u, 0u);
        *reinterpret_cast<uint4*>(&pa[tid][128]) = make_uint4(0u, 0u, 0u, 0u);
    } else {
        const int t2  = tid - 128;
        const int buf = t2 >> 6, o = (t2 >> 1) & 31, half = t2 & 1;
        *reinterpret_cast<uint4*>(&wt[buf][o][120 + half * 8]) = make_uint4(0u, 0u, 0u, 0u);
    }
    // ---- W for position 0 ----
    stage_w(w + (size_t)pos0 * (OC * 75), tid, wt[0], 0);
    __syncthreads();

    // ---- hoist A-fragments into registers (reused by all 4 positions) ----
    short8 af[4][2];
    #pragma unroll
    for (int ks = 0; ks < 4; ++ks) {
        const int koff = ks * 32 + lgrp * 8;
        af[ks][0] = *(const short8*)&pa[mbase + lrow][koff];
        af[ks][1] = *(const short8*)&pa[mbase + 16 + lrow][koff];
    }

    // ---- position loop: stage W[xi+1] overlaps MFMA[xi]; 1 barrier/position ----
    #pragma unroll
    for (int xi = 0; xi < XT; ++xi) {
        const int cur = xi & 1;
        if (xi + 1 < XT)
            stage_w(w + (size_t)(pos0 + xi + 1) * (OC * 75), tid, wt[cur ^ 1], xi + 1);

        f32x4 acc[2][2];
        #pragma unroll
        for (int mt = 0; mt < 2; ++mt)
            #pragma unroll
            for (int nt = 0; nt < 2; ++nt)
                acc[mt][nt] = (f32x4){0.f, 0.f, 0.f, 0.f};

        #pragma unroll
        for (int ks = 0; ks < 4; ++ks) {
            const int koff = ks * 32 + lgrp * 8;
            const short8 bf0 = *(const short8*)&wt[cur][lrow][koff];
            const short8 bf1 = *(const short8*)&wt[cur][16 + lrow][koff];
            acc[0][0] = __builtin_amdgcn_mfma_f32_16x16x32_bf16(af[ks][0], bf0, acc[0][0], 0, 0, 0);
            acc[0][1] = __builtin_amdgcn_mfma_f32_16x16x32_bf16(af[ks][0], bf1, acc[0][1], 0, 0, 0);
            acc[1][0] = __builtin_amdgcn_mfma_f32_16x16x32_bf16(af[ks][1], bf0, acc[1][0], 0, 0, 0);
            acc[1][1] = __builtin_amdgcn_mfma_f32_16x16x32_bf16(af[ks][1], bf1, acc[1][1], 0, 0, 0);
        }

        const int pos = pos0 + xi;
        if (COAL) {
            float* tb = tmp + (size_t)pos * (BATCH * OC);
            #pragma unroll
            for (int mt = 0; mt < 2; ++mt) {
                #pragma unroll
                for (int nt = 0; nt < 2; ++nt) {
                    const int o = nt * 16 + lrow;
                    #pragma unroll
                    for (int r = 0; r < 4; ++r) {
                        const int b = mbase + mt * 16 + lgrp * 4 + r;
                        tb[b * OC + o] = acc[mt][nt][r] + bb[xi][nt];
                    }
                }
            }
        } else {
            #pragma unroll
            for (int mt = 0; mt < 2; ++mt) {
                #pragma unroll
                for (int nt = 0; nt < 2; ++nt) {
                    const int o = nt * 16 + lrow;
                    #pragma unroll
                    for (int r = 0; r < 4; ++r) {
                        const int b = mbase + mt * 16 + lgrp * 4 + r;
                        outp[(size_t)(b * OC + o) * (RY * RX) + pos] = acc[mt][nt][r] + bb[xi][nt];
                    }
                }
            }
        }
        __syncthreads();
    }
}

// Phase 2: tmp[y*60+x][c] -> out[c][y*60+x], c = b*32+o in [0,4096)
__global__ __launch_bounds__(256) void lc2d_k2(
    const float* __restrict__ tmp, float* __restrict__ out)
{
    __shared__ float tile[64][61];
    const int y  = blockIdx.y;
    const int cb = blockIdx.x * 64;

    for (int i = threadIdx.x; i < RX * 16; i += 256) {
        const int xx  = i >> 4;
        const int cl4 = (i & 15) * 4;
        const float4 v = *(const float4*)(tmp + (size_t)(y * RX + xx) * (BATCH * OC) + cb + cl4);
        tile[cl4][xx]     = v.x;
        tile[cl4 + 1][xx] = v.y;
        tile[cl4 + 2][xx] = v.z;
        tile[cl4 + 3][xx] = v.w;
    }
    __syncthreads();

    for (int i = threadIdx.x; i < 64 * RX; i += 256) {
        const int cl = i / RX;
        const int xx = i % RX;
        out[(size_t)(cb + cl) * (RY * RX) + y * RX + xx] = tile[cl][xx];
    }
}

extern "C" void kernel_launch(void* const* d_in, const int* in_sizes, int n_in,
                              void* d_out, int out_size, void* d_ws, size_t ws_size,
                              hipStream_t stream) {
    const float* x    = (const float*)d_in[0];
    const float* w    = (const float*)d_in[1];
    const float* bias = (const float*)d_in[2];
    float* out        = (float*)d_out;
    float* tmp        = (float*)d_ws;

    const size_t tmp_bytes = (size_t)RY * RX * BATCH * OC * sizeof(float); // 59 MB

    if (ws_size >= tmp_bytes) {
        lc2d_k1<true><<<900, 256, 0, stream>>>(x, w, bias, out, tmp);
        lc2d_k2<<<dim3(64, RY), 256, 0, stream>>>(tmp, out);
    } else {
        lc2d_k1<false><<<900, 256, 0, stream>>>(x, w, bias, out, tmp);
    }
}